// Round 3
// baseline (114.919 us; speedup 1.0000x reference)
//
#include <hip/hip_runtime.h>
#include <hip/hip_cooperative_groups.h>

namespace cg = cooperative_groups;

// NetCrossing: soft segment-crossing count, one scalar out.
// o(u,v) = sig(u)sig(-v)+sig(-u)sig(v) with sig(x)=1/(1+e^{-5x}).
// With t_u=e^{-5u}: o(u,v) = (t_u+t_v)/((1+t_u)(1+t_v))
// => cross = o(d1,d2)*o(d3,d4) = (t1+t2)(t3+t4) / prod(1+t_i)  -- ONE divide.
#define KSIG 5.0f
#define ECLAMP 22.0f   // e^22 ~ 3.6e9; (1+t)^4 <= 1.7e38 stays finite in fp32

__device__ __forceinline__ float net_local_sum(
    const float* __restrict__ pos, const int* __restrict__ fnp,
    const int* __restrict__ nps, const unsigned char* __restrict__ mask_raw,
    bool mask_is_i32, int n, int num_pins)
{
    const int s = nps[n];
    const int e = nps[n + 1];
    const int d = e - s;                       // degree
    if (d < 4) return 0.0f;                    // need a (i, i+2) segment pair
    const bool m = mask_is_i32 ? (((const int*)mask_raw)[n] != 0)
                               : (mask_raw[n] != 0);
    if (!m) return 0.0f;

    float X[8], Y[8];
    #pragma unroll
    for (int k = 0; k < 8; ++k) {
        if (k < d) {
            const int pid = fnp[s + k];
            X[k] = pos[pid];
            Y[k] = pos[num_pins + pid];
        } else { X[k] = 0.0f; Y[k] = 0.0f; }
    }

    float local = 0.0f;
    #pragma unroll
    for (int i = 0; i <= 4; ++i) {
        if (i <= d - 4) {
            const float ax = X[i],   ay = Y[i];
            const float bx = X[i+1], by = Y[i+1];
            const float abx = bx - ax, aby = by - ay;
            #pragma unroll
            for (int j = i + 2; j <= 6; ++j) {
                if (j <= d - 2) {
                    const float cx = X[j],   cy = Y[j];
                    const float ex = X[j+1], ey = Y[j+1];
                    const float cax = cx - ax, cay = cy - ay;
                    const float eax = ex - ax, eay = ey - ay;
                    const float d1 = cax*eay - cay*eax;                      // ccw(A,C,E)
                    const float d2 = (cx-bx)*(ey-by) - (cy-by)*(ex-bx);      // ccw(B,C,E)
                    const float d3 = abx*cay - aby*cax;                      // ccw(A,B,C)
                    const float d4 = abx*eay - aby*eax;                      // ccw(A,B,E)
                    const float t1 = __expf(fminf(-KSIG*d1, ECLAMP));
                    const float t2 = __expf(fminf(-KSIG*d2, ECLAMP));
                    const float t3 = __expf(fminf(-KSIG*d3, ECLAMP));
                    const float t4 = __expf(fminf(-KSIG*d4, ECLAMP));
                    const float num = (t1 + t2) * (t3 + t4);
                    const float den = (1.0f+t1)*(1.0f+t2)*(1.0f+t3)*(1.0f+t4);
                    local += __fdividef(num, den);
                }
            }
        }
    }
    return local;
}

__device__ __forceinline__ float block_reduce_256(float v, float* lds4)
{
    #pragma unroll
    for (int off = 32; off > 0; off >>= 1) v += __shfl_down(v, off, 64);
    const int lane = threadIdx.x & 63, wid = threadIdx.x >> 6;
    if (lane == 0) lds4[wid] = v;
    __syncthreads();
    return lds4[0] + lds4[1] + lds4[2] + lds4[3];
}

// ---- single-dispatch cooperative version -----------------------------------
__global__ void __launch_bounds__(256, 4)
net_cross_coop(const float* __restrict__ pos, const int* __restrict__ fnp,
               const int* __restrict__ nps, const unsigned char* __restrict__ mask_raw,
               int num_nets, int num_pins, int npt, int nblocks,
               float* __restrict__ partials, float* __restrict__ out)
{
    __shared__ float lds4[4];
    const bool mask_is_i32 = (mask_raw[1] == 0);   // byte-bool vs int32 probe
    const int tid = blockIdx.x * 256 + threadIdx.x;
    const int tot = nblocks * 256;

    float local = 0.0f;
    for (int it = 0; it < npt; ++it) {
        const int n = tid + it * tot;              // consecutive nets per wave
        if (n < num_nets)
            local += net_local_sum(pos, fnp, nps, mask_raw, mask_is_i32, n, num_pins);
    }
    const float bsum = block_reduce_256(local, lds4);
    if (threadIdx.x == 0) partials[blockIdx.x] = bsum;

    cg::this_grid().sync();

    if (blockIdx.x == 0) {                         // deterministic final reduce
        float v = 0.0f;
        for (int i = threadIdx.x; i < nblocks; i += 256) v += partials[i];
        __syncthreads();                           // LDS reuse guard
        const float tsum = block_reduce_256(v, lds4);
        if (threadIdx.x == 0) out[0] = tsum;
    }
}

// ---- fallback: two-dispatch deterministic path -----------------------------
__global__ void __launch_bounds__(256)
net_cross_plain(const float* __restrict__ pos, const int* __restrict__ fnp,
                const int* __restrict__ nps, const unsigned char* __restrict__ mask_raw,
                int num_nets, int num_pins, float* __restrict__ partials)
{
    __shared__ float lds4[4];
    const bool mask_is_i32 = (mask_raw[1] == 0);
    const int n = blockIdx.x * 256 + threadIdx.x;
    float local = 0.0f;
    if (n < num_nets)
        local = net_local_sum(pos, fnp, nps, mask_raw, mask_is_i32, n, num_pins);
    const float bsum = block_reduce_256(local, lds4);
    if (threadIdx.x == 0) partials[blockIdx.x] = bsum;
}

__global__ void __launch_bounds__(256)
reduce_plain(const float* __restrict__ partials, int nb, float* __restrict__ out)
{
    __shared__ float lds4[4];
    float v = 0.0f;
    for (int i = threadIdx.x; i < nb; i += 256) v += partials[i];
    const float tsum = block_reduce_256(v, lds4);
    if (threadIdx.x == 0) out[0] = tsum;
}

extern "C" void kernel_launch(void* const* d_in, const int* in_sizes, int n_in,
                              void* d_out, int out_size, void* d_ws, size_t ws_size,
                              hipStream_t stream)
{
    const float*         pos  = (const float*)d_in[0];
    const int*           fnp  = (const int*)d_in[1];
    const int*           nps  = (const int*)d_in[2];
    const unsigned char* mask = (const unsigned char*)d_in[3];

    const int num_nets = in_sizes[2] - 1;
    const int num_pins = in_sizes[0] / 2;
    const int needed   = (num_nets + 255) / 256;

    // occupancy-bounded cooperative grid (256 CUs on MI355X); host-only query,
    // graph-capture safe.
    int maxPerCU = 0;
    if (hipOccupancyMaxActiveBlocksPerMultiprocessor(
            &maxPerCU, reinterpret_cast<const void*>(net_cross_coop), 256, 0)
            != hipSuccess || maxPerCU <= 0)
        maxPerCU = 4;
    int grid = maxPerCU * 256;
    if (grid > needed) grid = needed;
    if (grid > 2048)  grid = 2048;
    int npt = (num_nets + grid * 256 - 1) / (grid * 256);

    float* partials = (float*)d_ws;
    float* out      = (float*)d_out;

    void* args[] = { (void*)&pos, (void*)&fnp, (void*)&nps, (void*)&mask,
                     (void*)&num_nets, (void*)&num_pins, (void*)&npt, (void*)&grid,
                     (void*)&partials, (void*)&out };
    hipError_t err = hipLaunchCooperativeKernel(
        reinterpret_cast<const void*>(net_cross_coop),
        dim3(grid), dim3(256), args, 0, stream);

    if (err != hipSuccess) {
        // deterministic two-dispatch fallback
        net_cross_plain<<<needed, 256, 0, stream>>>(pos, fnp, nps, mask,
                                                    num_nets, num_pins, partials);
        reduce_plain<<<1, 256, 0, stream>>>(partials, needed, out);
    }
}

// Round 4
// 41.127 us; speedup vs baseline: 2.7942x; 2.7942x over previous
//
#include <hip/hip_runtime.h>

// NetCrossing: soft segment-crossing count -> one scalar.
// cross = (t1+t2)(t3+t4) / prod(1+t_i), t_i = e^{-5*d_i}  (one divide/pair)
#define KSIG   5.0f
#define ECLAMP 22.0f   // e^22~3.6e9; (1+t)^4 <= 1.7e38 finite in fp32
#define NPB    256     // nets per block
#define WCAP   2048    // staged pin-window capacity (actual max ~1286 here)

__global__ void __launch_bounds__(256)
net_cross_kernel(const float* __restrict__ pos,
                 const int* __restrict__ fnp,
                 const int* __restrict__ nps,
                 const unsigned char* __restrict__ mask_raw,
                 int num_nets, int num_pins,
                 float* __restrict__ out)
{
    __shared__ float2 smp[WCAP];
    __shared__ float  lds4[4];

    const int tid   = threadIdx.x;
    const int n0    = blockIdx.x * NPB;
    const int nlast = min(n0 + NPB, num_nets);

    const int w     = nps[n0];      // block-uniform -> s_load
    const int wend  = nps[nlast];
    const int wsize = min(wend - w, WCAP);

    // Stage (x,y) of every pin in this block's flat_netpin window into LDS.
    // fnp reads coalesced; pos gathered ONCE per pin (vs 8x per net).
    for (int slot = tid; slot < wsize; slot += 256) {
        const int pid = fnp[w + slot];
        smp[slot] = make_float2(pos[pid], pos[num_pins + pid]);
    }
    __syncthreads();

    // mask layout probe: bool-as-byte -> byte1 = mask[1] = 1; int32 -> 0
    const bool mask_is_i32 = (mask_raw[1] == 0);

    float local = 0.0f;
    const int n = n0 + tid;
    if (n < num_nets) {
        const int s = nps[n];
        const int e = nps[n + 1];
        const int d = min(e - s, 8);            // reference truncates at D=8
        const bool m = mask_is_i32 ? (((const int*)mask_raw)[n] != 0)
                                   : (mask_raw[n] != 0);
        if (d >= 4 && m) {                      // need a (i,i+2) segment pair
            float X[8], Y[8];
            if (e - 1 - w < WCAP) {             // window hit (always, here)
                const int b = s - w;
                #pragma unroll
                for (int k = 0; k < 8; ++k) {
                    const int kc = (k < d) ? k : (d - 1);   // clamp like idx_c
                    const float2 p2 = smp[b + kc];
                    X[k] = p2.x; Y[k] = p2.y;
                }
            } else {                            // generic fallback (never here)
                #pragma unroll
                for (int k = 0; k < 8; ++k) {
                    const int kc  = (k < d) ? k : (d - 1);
                    const int pid = fnp[s + kc];
                    X[k] = pos[pid]; Y[k] = pos[num_pins + pid];
                }
            }
            #pragma unroll
            for (int i = 0; i <= 4; ++i) {
                if (i <= d - 4) {
                    const float ax = X[i],   ay = Y[i];
                    const float bx = X[i+1], by = Y[i+1];
                    const float abx = bx - ax, aby = by - ay;
                    #pragma unroll
                    for (int j = i + 2; j <= 6; ++j) {
                        if (j <= d - 2) {
                            const float cx = X[j],   cy = Y[j];
                            const float ex = X[j+1], ey = Y[j+1];
                            const float cax = cx - ax, cay = cy - ay;
                            const float eax = ex - ax, eay = ey - ay;
                            const float d1 = cax*eay - cay*eax;                 // ccw(A,C,E)
                            const float d2 = (cx-bx)*(ey-by) - (cy-by)*(ex-bx); // ccw(B,C,E)
                            const float d3 = abx*cay - aby*cax;                 // ccw(A,B,C)
                            const float d4 = abx*eay - aby*eax;                 // ccw(A,B,E)
                            const float t1 = __expf(fminf(-KSIG*d1, ECLAMP));
                            const float t2 = __expf(fminf(-KSIG*d2, ECLAMP));
                            const float t3 = __expf(fminf(-KSIG*d3, ECLAMP));
                            const float t4 = __expf(fminf(-KSIG*d4, ECLAMP));
                            const float num = (t1 + t2) * (t3 + t4);
                            const float den = (1.0f+t1)*(1.0f+t2)*(1.0f+t3)*(1.0f+t4);
                            local += __fdividef(num, den);
                        }
                    }
                }
            }
        }
    }

    // wave shfl -> LDS across 4 waves -> one atomic per block
    #pragma unroll
    for (int off = 32; off > 0; off >>= 1) local += __shfl_down(local, off, 64);
    const int lane = tid & 63, wid = tid >> 6;
    if (lane == 0) lds4[wid] = local;
    __syncthreads();
    if (tid == 0)
        atomicAdd(out, lds4[0] + lds4[1] + lds4[2] + lds4[3]);   // MU = 1
}

extern "C" void kernel_launch(void* const* d_in, const int* in_sizes, int n_in,
                              void* d_out, int out_size, void* d_ws, size_t ws_size,
                              hipStream_t stream)
{
    const float*         pos  = (const float*)d_in[0];
    const int*           fnp  = (const int*)d_in[1];
    const int*           nps  = (const int*)d_in[2];
    const unsigned char* mask = (const unsigned char*)d_in[3];

    const int num_nets = in_sizes[2] - 1;
    const int num_pins = in_sizes[0] / 2;
    const int nb = (num_nets + NPB - 1) / NPB;

    hipMemsetAsync(d_out, 0, sizeof(float) * out_size, stream);
    net_cross_kernel<<<nb, 256, 0, stream>>>(pos, fnp, nps, mask,
                                             num_nets, num_pins, (float*)d_out);
}

// Round 5
// 20.595 us; speedup vs baseline: 5.5799x; 1.9969x over previous
//
#include <hip/hip_runtime.h>

// NetCrossing -> one scalar.
// cross = (t1+t2)(t3+t4) / prod(1+t_i), t_i = e^{-5*d_i}   (one divide/pair)
//
// Structure: block = 448 threads (7 waves) owns 448 CONSECUTIVE nets.
//  - stage the block's contiguous flat_netpin window into LDS (coalesced);
//  - wave w, lane l -> net n0 + w + 7l: with deg = 2 + n%7 all lanes of a
//    wave share one degree -> unrolled pair bodies are wave-uniform
//    (s_cbranch-skipped); scattered reads hit LDS, not L1 lines.
//  - deterministic: partials[block] -> tiny 1-block reduce (no atomics).
#define KSIG   5.0f
#define ECLAMP 22.0f    // e^22 ~ 3.6e9; (1+t)^4 <= 1.7e38 finite in fp32
#define NPB    448      // nets per block (7 waves * 64)
#define WCAP   2368     // pin-window capacity (actual max here: ~2242)

__global__ void __launch_bounds__(448)
net_cross_kernel(const float* __restrict__ pos,
                 const int* __restrict__ fnp,
                 const int* __restrict__ nps,
                 const unsigned char* __restrict__ mask_raw,
                 int num_nets, int num_pins,
                 float* __restrict__ partials)
{
    __shared__ float2 smp[WCAP];
    __shared__ float  lds7[7];

    const int tid  = threadIdx.x;
    const int lane = tid & 63;
    const int w    = tid >> 6;                 // wave id 0..6
    const int n0   = blockIdx.x * NPB;
    const int nlast = min(n0 + NPB, num_nets);

    const int w0    = nps[n0];                 // block-uniform
    const int wend  = nps[nlast];
    const int wsize = wend - w0;
    const bool use_lds = (wsize <= WCAP);

    if (use_lds) {
        // coalesced: fnp contiguous; pos[pid] contiguous when fnp is identity
        for (int slot = tid; slot < wsize; slot += NPB) {
            const int pid = fnp[w0 + slot];
            smp[slot] = make_float2(pos[pid], pos[num_pins + pid]);
        }
    }
    __syncthreads();

    // mask layout probe: bool-as-byte -> byte1 = mask[1] = 1; int32 -> 0
    const bool mask_is_i32 = (mask_raw[1] == 0);

    float local = 0.0f;
    const int n = n0 + w + 7 * lane;           // degree-uniform per wave
    if (n < num_nets) {
        const int s = nps[n];
        const int e = nps[n + 1];
        const int d = min(e - s, 8);           // reference truncates at D=8
        const bool m = mask_is_i32 ? (((const int*)mask_raw)[n] != 0)
                                   : (mask_raw[n] != 0);
        if (d >= 4 && m) {                     // need a (i, i+2) segment pair
            float X[8], Y[8];
            if (use_lds) {
                const int b = s - w0;
                #pragma unroll
                for (int k = 0; k < 8; ++k) {
                    if (k < d) { const float2 p2 = smp[b + k]; X[k] = p2.x; Y[k] = p2.y; }
                    else       { X[k] = 0.0f; Y[k] = 0.0f; }
                }
            } else {                           // generic fallback
                #pragma unroll
                for (int k = 0; k < 8; ++k) {
                    if (k < d) { const int pid = fnp[s + k]; X[k] = pos[pid]; Y[k] = pos[num_pins + pid]; }
                    else       { X[k] = 0.0f; Y[k] = 0.0f; }
                }
            }
            #pragma unroll
            for (int i = 0; i <= 4; ++i) {
                if (i <= d - 4) {              // wave-uniform -> execz skip
                    const float ax = X[i],   ay = Y[i];
                    const float bx = X[i+1], by = Y[i+1];
                    const float abx = bx - ax, aby = by - ay;
                    #pragma unroll
                    for (int j = i + 2; j <= 6; ++j) {
                        if (j <= d - 2) {
                            const float cx = X[j],   cy = Y[j];
                            const float ex = X[j+1], ey = Y[j+1];
                            const float cax = cx - ax, cay = cy - ay;
                            const float eax = ex - ax, eay = ey - ay;
                            const float d1 = cax*eay - cay*eax;                 // ccw(A,C,E)
                            const float d2 = (cx-bx)*(ey-by) - (cy-by)*(ex-bx); // ccw(B,C,E)
                            const float d3 = abx*cay - aby*cax;                 // ccw(A,B,C)
                            const float d4 = abx*eay - aby*eax;                 // ccw(A,B,E)
                            const float t1 = __expf(fminf(-KSIG*d1, ECLAMP));
                            const float t2 = __expf(fminf(-KSIG*d2, ECLAMP));
                            const float t3 = __expf(fminf(-KSIG*d3, ECLAMP));
                            const float t4 = __expf(fminf(-KSIG*d4, ECLAMP));
                            const float num = (t1 + t2) * (t3 + t4);
                            const float den = (1.0f+t1)*(1.0f+t2)*(1.0f+t3)*(1.0f+t4);
                            local += __fdividef(num, den);
                        }
                    }
                }
            }
        }
    }

    // wave shfl -> per-wave LDS slot -> thread 0 stores block partial
    #pragma unroll
    for (int off = 32; off > 0; off >>= 1) local += __shfl_down(local, off, 64);
    if (lane == 0) lds7[w] = local;
    __syncthreads();
    if (tid == 0) {
        float v = 0.0f;
        #pragma unroll
        for (int k = 0; k < 7; ++k) v += lds7[k];
        partials[blockIdx.x] = v;
    }
}

__global__ void __launch_bounds__(256)
reduce_kernel(const float* __restrict__ partials, int nb, float* __restrict__ out)
{
    __shared__ float lds4[4];
    float v = 0.0f;
    for (int i = threadIdx.x; i < nb; i += 256) v += partials[i];
    #pragma unroll
    for (int off = 32; off > 0; off >>= 1) v += __shfl_down(v, off, 64);
    const int lane = threadIdx.x & 63, wid = threadIdx.x >> 6;
    if (lane == 0) lds4[wid] = v;
    __syncthreads();
    if (threadIdx.x == 0) out[0] = lds4[0] + lds4[1] + lds4[2] + lds4[3];  // MU = 1
}

extern "C" void kernel_launch(void* const* d_in, const int* in_sizes, int n_in,
                              void* d_out, int out_size, void* d_ws, size_t ws_size,
                              hipStream_t stream)
{
    const float*         pos  = (const float*)d_in[0];
    const int*           fnp  = (const int*)d_in[1];
    const int*           nps  = (const int*)d_in[2];
    const unsigned char* mask = (const unsigned char*)d_in[3];

    const int num_nets = in_sizes[2] - 1;
    const int num_pins = in_sizes[0] / 2;
    const int nb = (num_nets + NPB - 1) / NPB;     // 1094 blocks

    float* partials = (float*)d_ws;                // nb * 4 B

    net_cross_kernel<<<nb, NPB, 0, stream>>>(pos, fnp, nps, mask,
                                             num_nets, num_pins, partials);
    reduce_kernel<<<1, 256, 0, stream>>>(partials, nb, (float*)d_out);
}